// Round 4
// baseline (1256.612 us; speedup 1.0000x reference)
//
#include <hip/hip_runtime.h>

#define N_NODES 50000
#define N_EDGES 800000
#define F_INP   32
#define HDIM    64
#define EDIM    16
#define COUT    40
#define NGRAPH  64

// ---------------------------------------------------------------- sort by dst
__global__ void hist_kernel(const int* __restrict__ dst, int* __restrict__ cnt, int E) {
    int e = blockIdx.x * 256 + threadIdx.x;
    if (e < E) atomicAdd(&cnt[dst[e]], 1);
}

__global__ void scan_part_kernel(const int* __restrict__ cnt, int* __restrict__ bsum, int n) {
    __shared__ int red[256];
    int tid = threadIdx.x;
    int idx = blockIdx.x * 256 + tid;
    red[tid] = (idx < n) ? cnt[idx] : 0;
    __syncthreads();
    for (int off = 128; off > 0; off >>= 1) {
        if (tid < off) red[tid] += red[tid + off];
        __syncthreads();
    }
    if (tid == 0) bsum[blockIdx.x] = red[0];
}

__global__ void scan_top_kernel(int* __restrict__ bsum, int nb) {
    __shared__ int tmp[256];
    int tid = threadIdx.x;
    int v = (tid < nb) ? bsum[tid] : 0;
    tmp[tid] = v;
    __syncthreads();
    for (int off = 1; off < 256; off <<= 1) {
        int x = (tid >= off) ? tmp[tid - off] : 0;
        __syncthreads();
        tmp[tid] += x;
        __syncthreads();
    }
    if (tid < nb) bsum[tid] = tmp[tid] - v;   // exclusive
}

__global__ void scan_apply_kernel(const int* __restrict__ cnt, const int* __restrict__ bsum,
                                  int* __restrict__ offsets, int* __restrict__ cursor, int n) {
    __shared__ int tmp[256];
    int tid = threadIdx.x;
    int idx = blockIdx.x * 256 + tid;
    int v = (idx < n) ? cnt[idx] : 0;
    tmp[tid] = v;
    __syncthreads();
    for (int off = 1; off < 256; off <<= 1) {
        int x = (tid >= off) ? tmp[tid - off] : 0;
        __syncthreads();
        tmp[tid] += x;
        __syncthreads();
    }
    int excl = tmp[tid] - v + bsum[blockIdx.x];
    if (idx < n) { offsets[idx] = excl; cursor[idx] = excl; }
    if (idx == n - 1) offsets[n] = excl + v;
}

__global__ void scatter_kernel(const int* __restrict__ dst, int* __restrict__ cursor,
                               int* __restrict__ sorted, int E) {
    int e = blockIdx.x * 256 + threadIdx.x;
    if (e < E) {
        int p = atomicAdd(&cursor[dst[e]], 1);
        sorted[p] = e;
    }
}

// gather edge_attr + src into dst-sorted order (streaming reads thereafter)
__global__ void permute_kernel(const int* __restrict__ sorted, const int* __restrict__ src,
                               const float4* __restrict__ ea, float4* __restrict__ ea_s,
                               int* __restrict__ src_s, int E) {
    int t = blockIdx.x * 256 + threadIdx.x;
    int j = t >> 2, q = t & 3;
    if (j >= E) return;
    int e = sorted[j];
    ea_s[(size_t)j * 4 + q] = ea[(size_t)e * 4 + q];
    if (q == 0) src_s[j] = src[e];
}

// batch is sorted ascending; find graph start offsets
__global__ void gstart_kernel(const int* __restrict__ batch, int* __restrict__ gstart,
                              int N, int G) {
    int n = blockIdx.x * 256 + threadIdx.x;
    if (n >= N) return;
    int g  = batch[n];
    int gp = (n == 0) ? -1 : batch[n - 1];
    for (int gg = gp + 1; gg <= g; gg++) gstart[gg] = n;
    if (n == N - 1) {
        for (int gg = g + 1; gg <= G; gg++) gstart[gg] = N;
    }
}

// ---------------------------------------------------------------- input linear
// h = x @ W + b  (N,32)@(32,64); grid-stride; epilogue: h stats (sum, sumsq)
__global__ void lin_in_kernel(const float* __restrict__ x, const float* __restrict__ W,
                              const float* __restrict__ b, float* __restrict__ h,
                              float* __restrict__ nstats, int N) {
    __shared__ float red[256];
    int tid = threadIdx.x;
    int c = tid & 63;
    float w[F_INP];
#pragma unroll
    for (int k = 0; k < F_INP; k++) w[k] = W[k * HDIM + c];
    float bc = b[c];
    float s = 0.f, ss = 0.f;
    for (int node = blockIdx.x * 4 + (tid >> 6); node < N; node += gridDim.x * 4) {
        const float4* xr = (const float4*)(x + (size_t)node * F_INP);
        float acc = bc;
#pragma unroll
        for (int k4 = 0; k4 < F_INP / 4; k4++) {
            float4 xv = xr[k4];
            acc += xv.x * w[4 * k4] + xv.y * w[4 * k4 + 1]
                 + xv.z * w[4 * k4 + 2] + xv.w * w[4 * k4 + 3];
        }
        h[(size_t)node * HDIM + c] = acc;
        s += acc; ss += acc * acc;
    }
    __syncthreads();
    red[tid] = s;
    __syncthreads();
    if (tid < 64) atomicAdd(&nstats[tid], red[tid] + red[tid + 64] + red[tid + 128] + red[tid + 192]);
    __syncthreads();
    red[tid] = ss;
    __syncthreads();
    if (tid < 64) atomicAdd(&nstats[64 + tid], red[tid] + red[tid + 64] + red[tid + 128] + red[tid + 192]);
}

// ---------------------------------------------------------------- aggregation
// one wave per node (lane = channel). BN+ReLU of h fused. We column in VGPRs.
// sorted==nullptr means ea/srcarr are already in dst-sorted order (fast path).
// No seg_max: m in [1e-7,~8], exp cannot overflow; softmax shift-invariant.
__global__ void agg_kernel(const float* __restrict__ h, const int* __restrict__ srcarr,
                           const float* __restrict__ ea, const float* __restrict__ We,
                           const float* __restrict__ be, const float* __restrict__ tptr,
                           const float* __restrict__ stats,
                           const float* __restrict__ gamma, const float* __restrict__ beta,
                           const int* __restrict__ offsets, const int* __restrict__ sorted,
                           float* __restrict__ out, int N) {
    int tid = threadIdx.x;
    int c = tid & 63;
    float inv = 1.0f / (float)N;
    float mu  = stats[c] * inv;
    float var = stats[HDIM + c] * inv - mu * mu;
    float rs  = rsqrtf(var + 1e-5f);
    float ga  = gamma[c], bb = beta[c];
    float w[EDIM];
#pragma unroll
    for (int k = 0; k < EDIM; k++) w[k] = We[k * HDIM + c];
    float bc = be[c];
    float tval = *tptr;
    int node = blockIdx.x * 4 + (tid >> 6);
    if (node >= N) return;
    int beg = offsets[node], end = offsets[node + 1];
    float denom = 0.f, num = 0.f;
    for (int cb = beg; cb < end; cb += 64) {
        int nc = end - cb; if (nc > 64) nc = 64;
        int e_l = 0, s_l = 0;
        if (c < nc) {
            e_l = sorted ? sorted[cb + c] : (cb + c);
            s_l = srcarr[e_l];
        }
        for (int j = 0; j < nc; j++) {
            int e = __shfl(e_l, j);
            int s = __shfl(s_l, j);
            const float4* ar = (const float4*)(ea + (size_t)e * EDIM);
            float4 a0 = ar[0], a1 = ar[1], a2 = ar[2], a3 = ar[3];
            float acc = bc
                + a0.x * w[0]  + a0.y * w[1]  + a0.z * w[2]  + a0.w * w[3]
                + a1.x * w[4]  + a1.y * w[5]  + a1.z * w[6]  + a1.w * w[7]
                + a2.x * w[8]  + a2.y * w[9]  + a2.z * w[10] + a2.w * w[11]
                + a3.x * w[12] + a3.y * w[13] + a3.z * w[14] + a3.w * w[15];
            float hv = h[(size_t)s * HDIM + c];
            float zv = fmaxf((hv - mu) * rs * ga + bb, 0.f);
            float m  = fmaxf(zv + acc, 0.f) + 1e-7f;
            float ex = __expf(m * tval);
            denom += ex;
            num   += ex * m;
        }
    }
    float hv = h[(size_t)node * HDIM + c];
    float zn = fmaxf((hv - mu) * rs * ga + bb, 0.f);
    out[(size_t)node * HDIM + c] = num / (denom + 1e-16f) + zn;
}

// ---------------------------------------------------------------- MLP part 1
// h1 = in @ W1 + b1  (N,64)@(64,128); grid-stride; epilogue: h1 stats
__global__ __launch_bounds__(256) void mlp1_kernel(
        const float* __restrict__ in, const float* __restrict__ W1,
        const float* __restrict__ b1, float* __restrict__ h1,
        float* __restrict__ stats, int N) {
    __shared__ float sW[HDIM * 128];         // 32 KB
    __shared__ float srow[32 * 68];          // pad 68: 16B-aligned float4 rows
    __shared__ float red[256];
    int tid = threadIdx.x;
    for (int i = tid; i < HDIM * 128 / 4; i += 256)
        ((float4*)sW)[i] = ((const float4*)W1)[i];
    int tx = tid & 31, ty = tid >> 5;
    float4 bv = *(const float4*)&b1[4 * tx];
    float s0 = 0, s1 = 0, s2 = 0, s3 = 0, q0 = 0, q1 = 0, q2 = 0, q3 = 0;
    int ntiles = (N + 31) >> 5;
    for (int tile = blockIdx.x; tile < ntiles; tile += gridDim.x) {
        int base = tile << 5;
        __syncthreads();
        for (int i = tid; i < 32 * 16; i += 256) {
            int r = i >> 4, q = i & 15;
            int node = base + r;
            float4 v = make_float4(0.f, 0.f, 0.f, 0.f);
            if (node < N) v = *(const float4*)&in[(size_t)node * HDIM + 4 * q];
            *(float4*)&srow[r * 68 + 4 * q] = v;
        }
        __syncthreads();
        float acc[4][4];
#pragma unroll
        for (int j = 0; j < 4; j++) { acc[j][0] = bv.x; acc[j][1] = bv.y; acc[j][2] = bv.z; acc[j][3] = bv.w; }
#pragma unroll
        for (int k4 = 0; k4 < 16; k4++) {
            float4 rv[4];
#pragma unroll
            for (int j = 0; j < 4; j++)
                rv[j] = *(const float4*)&srow[(ty * 4 + j) * 68 + 4 * k4];
#pragma unroll
            for (int kk = 0; kk < 4; kk++) {
                float4 wv = *(const float4*)&sW[(k4 * 4 + kk) * 128 + 4 * tx];
#pragma unroll
                for (int j = 0; j < 4; j++) {
                    float f = ((const float*)&rv[j])[kk];
                    acc[j][0] += f * wv.x; acc[j][1] += f * wv.y;
                    acc[j][2] += f * wv.z; acc[j][3] += f * wv.w;
                }
            }
        }
#pragma unroll
        for (int j = 0; j < 4; j++) {
            int node = base + ty * 4 + j;
            if (node < N) {
                *(float4*)&h1[(size_t)node * 128 + 4 * tx] =
                    make_float4(acc[j][0], acc[j][1], acc[j][2], acc[j][3]);
                s0 += acc[j][0]; q0 += acc[j][0] * acc[j][0];
                s1 += acc[j][1]; q1 += acc[j][1] * acc[j][1];
                s2 += acc[j][2]; q2 += acc[j][2] * acc[j][2];
                s3 += acc[j][3]; q3 += acc[j][3] * acc[j][3];
            }
        }
    }
    float sq[8] = { s0, s1, s2, s3, q0, q1, q2, q3 };
#pragma unroll
    for (int q = 0; q < 8; q++) {
        __syncthreads();
        red[tid] = sq[q];
        __syncthreads();
        if (tid < 32) {
            float t = 0.f;
#pragma unroll
            for (int k = 0; k < 8; k++) t += red[tid + 32 * k];
            atomicAdd(&stats[(q < 4 ? 0 : 128) + 4 * tid + (q & 3)], t);
        }
    }
}

// ---------------------------------------------------------------- MLP part 2
// h += relu(BN(h1)) @ W2 + b2; grid-stride; epilogue: stats of NEW h
__global__ __launch_bounds__(256) void mlp2_kernel(
        const float* __restrict__ h1, const float* __restrict__ stats,
        const float* __restrict__ mg, const float* __restrict__ mb,
        const float* __restrict__ W2, const float* __restrict__ b2,
        float* __restrict__ h, float* __restrict__ nstats, int N) {
    __shared__ float sW[128 * HDIM];         // 32 KB
    __shared__ float sact[32 * 132];         // pad 132: 16B-aligned
    __shared__ float sbn[512];               // mu | rs | gamma | beta
    __shared__ float red[256];
    int tid = threadIdx.x;
    for (int i = tid; i < 128 * HDIM / 4; i += 256)
        ((float4*)sW)[i] = ((const float4*)W2)[i];
    if (tid < 128) {
        float inv = 1.0f / (float)N;
        float mu  = stats[tid] * inv;
        float var = stats[128 + tid] * inv - mu * mu;
        sbn[tid]       = mu;
        sbn[128 + tid] = rsqrtf(var + 1e-5f);
        sbn[256 + tid] = mg[tid];
        sbn[384 + tid] = mb[tid];
    }
    int tx = tid & 15, ty = tid >> 4;
    float4 bv = *(const float4*)&b2[4 * tx];
    float s0 = 0, s1 = 0, s2 = 0, s3 = 0, q0 = 0, q1 = 0, q2 = 0, q3 = 0;
    int ntiles = (N + 31) >> 5;
    for (int tile = blockIdx.x; tile < ntiles; tile += gridDim.x) {
        int base = tile << 5;
        __syncthreads();
        for (int i = tid; i < 32 * 32; i += 256) {
            int r = i >> 5, q = i & 31;
            int node = base + r;
            float4 v = make_float4(0.f, 0.f, 0.f, 0.f);
            if (node < N) {
                v = *(const float4*)&h1[(size_t)node * 128 + 4 * q];
                int o = 4 * q;
                v.x = fmaxf((v.x - sbn[o + 0]) * sbn[128 + o + 0] * sbn[256 + o + 0] + sbn[384 + o + 0], 0.f);
                v.y = fmaxf((v.y - sbn[o + 1]) * sbn[128 + o + 1] * sbn[256 + o + 1] + sbn[384 + o + 1], 0.f);
                v.z = fmaxf((v.z - sbn[o + 2]) * sbn[128 + o + 2] * sbn[256 + o + 2] + sbn[384 + o + 2], 0.f);
                v.w = fmaxf((v.w - sbn[o + 3]) * sbn[128 + o + 3] * sbn[256 + o + 3] + sbn[384 + o + 3], 0.f);
            }
            *(float4*)&sact[r * 132 + 4 * q] = v;
        }
        __syncthreads();
        float acc[2][4];
#pragma unroll
        for (int j = 0; j < 2; j++) { acc[j][0] = bv.x; acc[j][1] = bv.y; acc[j][2] = bv.z; acc[j][3] = bv.w; }
#pragma unroll
        for (int k4 = 0; k4 < 32; k4++) {
            float4 r0 = *(const float4*)&sact[(ty * 2 + 0) * 132 + 4 * k4];
            float4 r1 = *(const float4*)&sact[(ty * 2 + 1) * 132 + 4 * k4];
#pragma unroll
            for (int kk = 0; kk < 4; kk++) {
                float4 wv = *(const float4*)&sW[(k4 * 4 + kk) * HDIM + 4 * tx];
                float f0 = ((const float*)&r0)[kk];
                float f1 = ((const float*)&r1)[kk];
                acc[0][0] += f0 * wv.x; acc[0][1] += f0 * wv.y; acc[0][2] += f0 * wv.z; acc[0][3] += f0 * wv.w;
                acc[1][0] += f1 * wv.x; acc[1][1] += f1 * wv.y; acc[1][2] += f1 * wv.z; acc[1][3] += f1 * wv.w;
            }
        }
#pragma unroll
        for (int j = 0; j < 2; j++) {
            int node = base + ty * 2 + j;
            if (node < N) {
                float4* p = (float4*)&h[(size_t)node * HDIM + 4 * tx];
                float4 old = *p;
                float4 nv = make_float4(old.x + acc[j][0], old.y + acc[j][1],
                                        old.z + acc[j][2], old.w + acc[j][3]);
                *p = nv;
                s0 += nv.x; q0 += nv.x * nv.x;
                s1 += nv.y; q1 += nv.y * nv.y;
                s2 += nv.z; q2 += nv.z * nv.z;
                s3 += nv.w; q3 += nv.w * nv.w;
            }
        }
    }
    float sq[8] = { s0, s1, s2, s3, q0, q1, q2, q3 };
#pragma unroll
    for (int q = 0; q < 8; q++) {
        __syncthreads();
        red[tid] = sq[q];
        __syncthreads();
        if (tid < 16) {
            float t = 0.f;
#pragma unroll
            for (int k = 0; k < 16; k++) t += red[tid + 16 * k];
            atomicAdd(&nstats[(q < 4 ? 0 : 64) + 4 * tid + (q & 3)], t);
        }
    }
}

// ---------------------------------------------------------------- pool + head
__global__ void pool_out_kernel(const float* __restrict__ h, const int* __restrict__ gstart,
                                const float* __restrict__ Wo, const float* __restrict__ bo,
                                float* __restrict__ out, int N) {
    __shared__ float sp[HDIM];
    __shared__ float red[256];
    __shared__ float sW[HDIM * COUT];
    int g = blockIdx.x;
    int tid = threadIdx.x;
    for (int i = tid; i < HDIM * COUT; i += 256) sW[i] = Wo[i];
    int beg = gstart[g], end = gstart[g + 1];
    int c = tid & 63, r0 = tid >> 6;
    float s = 0.f;
    for (int r = beg + r0; r < end; r += 4) s += h[(size_t)r * HDIM + c];
    red[tid] = s;
    __syncthreads();
    if (tid < HDIM) {
        s = red[tid] + red[tid + 64] + red[tid + 128] + red[tid + 192];
        float cnt = (float)(end - beg);
        float pooled = s / fmaxf(cnt, 1.0f);
        sp[tid] = fmaxf(pooled, 0.0f);
    }
    __syncthreads();
    if (tid < COUT) {
        float acc = bo[tid];
#pragma unroll
        for (int k = 0; k < HDIM; k++) acc += sp[k] * sW[k * COUT + tid];
        out[g * COUT + tid] = acc;
    }
}

// ================================================================ launch
extern "C" void kernel_launch(void* const* d_in, const int* in_sizes, int n_in,
                              void* d_out, int out_size, void* d_ws, size_t ws_size,
                              hipStream_t stream) {
    (void)in_sizes; (void)n_in; (void)out_size;
    const float* x          = (const float*)d_in[0];
    const int*   eidx       = (const int*)  d_in[1];
    const float* eattr      = (const float*)d_in[2];
    const int*   batch      = (const int*)  d_in[3];
    const float* lin_in_w   = (const float*)d_in[4];
    const float* lin_in_b   = (const float*)d_in[5];
    const float* norm_gamma = (const float*)d_in[6];
    const float* norm_beta  = (const float*)d_in[7];
    const float* edge_w     = (const float*)d_in[8];
    const float* edge_b     = (const float*)d_in[9];
    const float* tparam     = (const float*)d_in[10];
    const float* mlp_w1     = (const float*)d_in[11];
    const float* mlp_b1     = (const float*)d_in[12];
    const float* mlp_gamma  = (const float*)d_in[13];
    const float* mlp_beta   = (const float*)d_in[14];
    const float* mlp_w2     = (const float*)d_in[15];
    const float* mlp_b2     = (const float*)d_in[16];
    const float* lin_out_w  = (const float*)d_in[17];
    const float* lin_out_b  = (const float*)d_in[18];
    float* out = (float*)d_out;

    const int* src = eidx;
    const int* dst = eidx + N_EDGES;

    char* ws = (char*)d_ws;
    size_t off = 0;
    auto alloc = [&](size_t bytes) -> char* {
        char* p = ws + off;
        off = (off + bytes + 255) & ~(size_t)255;
        return p;
    };
    // zero-init region first: histogram + all BN stat accumulators
    int*   cnt     = (int*)  alloc((size_t)N_NODES * 4);
    float* statsA0 = (float*)alloc(128 * 4);   // h stats, layer 0
    float* statsB0 = (float*)alloc(256 * 4);   // h1 stats, layer 0
    float* statsA1 = (float*)alloc(128 * 4);   // h stats, layer 1 (from mlp2 l0)
    float* statsB1 = (float*)alloc(256 * 4);   // h1 stats, layer 1
    float* statsA2 = (float*)alloc(128 * 4);   // dummy sink (mlp2 l1)
    size_t zero_bytes = off;
    int*   bsum    = (int*)  alloc(256 * 4);
    int*   offsets = (int*)  alloc((size_t)(N_NODES + 1) * 4);
    int*   cursor  = (int*)  alloc((size_t)N_NODES * 4);
    int*   sorted  = (int*)  alloc((size_t)N_EDGES * 4);
    int*   gstart  = (int*)  alloc((size_t)(NGRAPH + 1) * 4);
    float* h       = (float*)alloc((size_t)N_NODES * HDIM * 4);
    float* ob      = (float*)alloc((size_t)N_NODES * HDIM * 4);
    float* h1      = (float*)alloc((size_t)N_NODES * 2 * HDIM * 4);
    // optional fast-path buffers (54.4 MB): edge data permuted into dst order
    size_t need_fast = off + (size_t)N_EDGES * 4 + 256 + (size_t)N_EDGES * EDIM * 4 + 256;
    bool fast = (ws_size >= need_fast);
    int*   src_sorted = nullptr;
    float* ea_sorted  = nullptr;
    if (fast) {
        src_sorted = (int*)  alloc((size_t)N_EDGES * 4);
        ea_sorted  = (float*)alloc((size_t)N_EDGES * EDIM * 4);
    }

    hipMemsetAsync(d_ws, 0, zero_bytes, stream);

    const int NB = (N_NODES + 255) / 256;
    hist_kernel      <<<(N_EDGES + 255) / 256, 256, 0, stream>>>(dst, cnt, N_EDGES);
    scan_part_kernel <<<NB, 256, 0, stream>>>(cnt, bsum, N_NODES);
    scan_top_kernel  <<<1, 256, 0, stream>>>(bsum, NB);
    scan_apply_kernel<<<NB, 256, 0, stream>>>(cnt, bsum, offsets, cursor, N_NODES);
    scatter_kernel   <<<(N_EDGES + 255) / 256, 256, 0, stream>>>(dst, cursor, sorted, N_EDGES);
    if (fast)
        permute_kernel<<<(N_EDGES * 4 + 255) / 256, 256, 0, stream>>>(
            sorted, src, (const float4*)eattr, (float4*)ea_sorted, src_sorted, N_EDGES);
    gstart_kernel    <<<NB, 256, 0, stream>>>(batch, gstart, N_NODES, NGRAPH);
    lin_in_kernel    <<<256, 256, 0, stream>>>(x, lin_in_w, lin_in_b, h, statsA0, N_NODES);

    float* statsA[3] = { statsA0, statsA1, statsA2 };
    float* statsB[2] = { statsB0, statsB1 };
    const int MLPG = 768;                    // grid-stride blocks for MLPs
    for (int l = 0; l < 2; l++) {
        agg_kernel<<<(N_NODES + 3) / 4, 256, 0, stream>>>(
            h,
            fast ? src_sorted : src,
            fast ? ea_sorted : eattr,
            edge_w + (size_t)l * EDIM * HDIM, edge_b + l * HDIM,
            tparam + l, statsA[l], norm_gamma + l * HDIM, norm_beta + l * HDIM,
            offsets, fast ? nullptr : sorted, ob, N_NODES);
        mlp1_kernel<<<MLPG, 256, 0, stream>>>(
            ob, mlp_w1 + (size_t)l * HDIM * 2 * HDIM, mlp_b1 + l * 2 * HDIM,
            h1, statsB[l], N_NODES);
        mlp2_kernel<<<MLPG, 256, 0, stream>>>(
            h1, statsB[l], mlp_gamma + l * 2 * HDIM, mlp_beta + l * 2 * HDIM,
            mlp_w2 + (size_t)l * 2 * HDIM * HDIM, mlp_b2 + l * HDIM,
            h, statsA[l + 1], N_NODES);
    }
    pool_out_kernel<<<NGRAPH, 256, 0, stream>>>(h, gstart, lin_out_w, lin_out_b, out, N_NODES);
}

// Round 5
// 947.164 us; speedup vs baseline: 1.3267x; 1.3267x over previous
//
#include <hip/hip_runtime.h>

#define N_NODES 50000
#define N_EDGES 800000
#define F_INP   32
#define HDIM    64
#define EDIM    16
#define COUT    40
#define NGRAPH  64

// ---------------------------------------------------------------- sort by dst
__global__ void hist_kernel(const int* __restrict__ dst, int* __restrict__ cnt, int E) {
    int e = blockIdx.x * 256 + threadIdx.x;
    if (e < E) atomicAdd(&cnt[dst[e]], 1);
}

__global__ void scan_part_kernel(const int* __restrict__ cnt, int* __restrict__ bsum, int n) {
    __shared__ int red[256];
    int tid = threadIdx.x;
    int idx = blockIdx.x * 256 + tid;
    red[tid] = (idx < n) ? cnt[idx] : 0;
    __syncthreads();
    for (int off = 128; off > 0; off >>= 1) {
        if (tid < off) red[tid] += red[tid + off];
        __syncthreads();
    }
    if (tid == 0) bsum[blockIdx.x] = red[0];
}

__global__ void scan_top_kernel(int* __restrict__ bsum, int nb) {
    __shared__ int tmp[256];
    int tid = threadIdx.x;
    int v = (tid < nb) ? bsum[tid] : 0;
    tmp[tid] = v;
    __syncthreads();
    for (int off = 1; off < 256; off <<= 1) {
        int x = (tid >= off) ? tmp[tid - off] : 0;
        __syncthreads();
        tmp[tid] += x;
        __syncthreads();
    }
    if (tid < nb) bsum[tid] = tmp[tid] - v;   // exclusive
}

__global__ void scan_apply_kernel(const int* __restrict__ cnt, const int* __restrict__ bsum,
                                  int* __restrict__ offsets, int* __restrict__ cursor, int n) {
    __shared__ int tmp[256];
    int tid = threadIdx.x;
    int idx = blockIdx.x * 256 + tid;
    int v = (idx < n) ? cnt[idx] : 0;
    tmp[tid] = v;
    __syncthreads();
    for (int off = 1; off < 256; off <<= 1) {
        int x = (tid >= off) ? tmp[tid - off] : 0;
        __syncthreads();
        tmp[tid] += x;
        __syncthreads();
    }
    int excl = tmp[tid] - v + bsum[blockIdx.x];
    if (idx < n) { offsets[idx] = excl; cursor[idx] = excl; }
    if (idx == n - 1) offsets[n] = excl + v;
}

__global__ void scatter_kernel(const int* __restrict__ dst, int* __restrict__ cursor,
                               int* __restrict__ sorted, int E) {
    int e = blockIdx.x * 256 + threadIdx.x;
    if (e < E) {
        int p = atomicAdd(&cursor[dst[e]], 1);
        sorted[p] = e;
    }
}

// gather edge_attr + src into dst-sorted order (streaming reads thereafter)
__global__ void permute_kernel(const int* __restrict__ sorted, const int* __restrict__ src,
                               const float4* __restrict__ ea, float4* __restrict__ ea_s,
                               int* __restrict__ src_s, int E) {
    int t = blockIdx.x * 256 + threadIdx.x;
    int j = t >> 2, q = t & 3;
    if (j >= E) return;
    int e = sorted[j];
    ea_s[(size_t)j * 4 + q] = ea[(size_t)e * 4 + q];
    if (q == 0) src_s[j] = src[e];
}

// batch is sorted ascending; find graph start offsets
__global__ void gstart_kernel(const int* __restrict__ batch, int* __restrict__ gstart,
                              int N, int G) {
    int n = blockIdx.x * 256 + threadIdx.x;
    if (n >= N) return;
    int g  = batch[n];
    int gp = (n == 0) ? -1 : batch[n - 1];
    for (int gg = gp + 1; gg <= g; gg++) gstart[gg] = n;
    if (n == N - 1) {
        for (int gg = g + 1; gg <= G; gg++) gstart[gg] = N;
    }
}

// ---------------------------------------------------------------- input linear
// h = x @ W + b  (N,32)@(32,64); grid-stride; epilogue: h stats (sum, sumsq)
__global__ void lin_in_kernel(const float* __restrict__ x, const float* __restrict__ W,
                              const float* __restrict__ b, float* __restrict__ h,
                              float* __restrict__ nstats, int N) {
    __shared__ float red[256];
    int tid = threadIdx.x;
    int c = tid & 63;
    float w[F_INP];
#pragma unroll
    for (int k = 0; k < F_INP; k++) w[k] = W[k * HDIM + c];
    float bc = b[c];
    float s = 0.f, ss = 0.f;
    for (int node = blockIdx.x * 4 + (tid >> 6); node < N; node += gridDim.x * 4) {
        const float4* xr = (const float4*)(x + (size_t)node * F_INP);
        float acc = bc;
#pragma unroll
        for (int k4 = 0; k4 < F_INP / 4; k4++) {
            float4 xv = xr[k4];
            acc += xv.x * w[4 * k4] + xv.y * w[4 * k4 + 1]
                 + xv.z * w[4 * k4 + 2] + xv.w * w[4 * k4 + 3];
        }
        h[(size_t)node * HDIM + c] = acc;
        s += acc; ss += acc * acc;
    }
    __syncthreads();
    red[tid] = s;
    __syncthreads();
    if (tid < 64) atomicAdd(&nstats[tid], red[tid] + red[tid + 64] + red[tid + 128] + red[tid + 192]);
    __syncthreads();
    red[tid] = ss;
    __syncthreads();
    if (tid < 64) atomicAdd(&nstats[64 + tid], red[tid] + red[tid + 64] + red[tid + 128] + red[tid + 192]);
}

// ---------------------------------------------------------------- aggregation
// one wave per node (lane = channel). BN+ReLU of h fused. We column in VGPRs.
// sorted==nullptr means ea/srcarr are already in dst-sorted order (fast path).
// No seg_max: m in [1e-7,~8], exp cannot overflow; softmax shift-invariant.
__global__ void agg_kernel(const float* __restrict__ h, const int* __restrict__ srcarr,
                           const float* __restrict__ ea, const float* __restrict__ We,
                           const float* __restrict__ be, const float* __restrict__ tptr,
                           const float* __restrict__ stats,
                           const float* __restrict__ gamma, const float* __restrict__ beta,
                           const int* __restrict__ offsets, const int* __restrict__ sorted,
                           float* __restrict__ out, int N) {
    int tid = threadIdx.x;
    int c = tid & 63;
    float inv = 1.0f / (float)N;
    float mu  = stats[c] * inv;
    float var = stats[HDIM + c] * inv - mu * mu;
    float rs  = rsqrtf(var + 1e-5f);
    float ga  = gamma[c], bb = beta[c];
    float w[EDIM];
#pragma unroll
    for (int k = 0; k < EDIM; k++) w[k] = We[k * HDIM + c];
    float bc = be[c];
    float tval = *tptr;
    int node = blockIdx.x * 4 + (tid >> 6);
    if (node >= N) return;
    int beg = offsets[node], end = offsets[node + 1];
    float denom = 0.f, num = 0.f;
    for (int cb = beg; cb < end; cb += 64) {
        int nc = end - cb; if (nc > 64) nc = 64;
        int e_l = 0, s_l = 0;
        if (c < nc) {
            e_l = sorted ? sorted[cb + c] : (cb + c);
            s_l = srcarr[e_l];
        }
        for (int j = 0; j < nc; j++) {
            int e = __shfl(e_l, j);
            int s = __shfl(s_l, j);
            const float4* ar = (const float4*)(ea + (size_t)e * EDIM);
            float4 a0 = ar[0], a1 = ar[1], a2 = ar[2], a3 = ar[3];
            float acc = bc
                + a0.x * w[0]  + a0.y * w[1]  + a0.z * w[2]  + a0.w * w[3]
                + a1.x * w[4]  + a1.y * w[5]  + a1.z * w[6]  + a1.w * w[7]
                + a2.x * w[8]  + a2.y * w[9]  + a2.z * w[10] + a2.w * w[11]
                + a3.x * w[12] + a3.y * w[13] + a3.z * w[14] + a3.w * w[15];
            float hv = h[(size_t)s * HDIM + c];
            float zv = fmaxf((hv - mu) * rs * ga + bb, 0.f);
            float m  = fmaxf(zv + acc, 0.f) + 1e-7f;
            float ex = __expf(m * tval);
            denom += ex;
            num   += ex * m;
        }
    }
    float hv = h[(size_t)node * HDIM + c];
    float zn = fmaxf((hv - mu) * rs * ga + bb, 0.f);
    out[(size_t)node * HDIM + c] = num / (denom + 1e-16f) + zn;
}

// ---------------------------------------------------------------- MLP part 1
// h1 = in @ W1 + b1  (N,64)@(64,128); grid-stride tiles; round-3 inner loop
// (scalar LDS activation reads, unroll 8 -> bounded register pressure);
// epilogue: h1 stats (sum, sumsq)
__global__ __launch_bounds__(256) void mlp1_kernel(
        const float* __restrict__ in, const float* __restrict__ W1,
        const float* __restrict__ b1, float* __restrict__ h1,
        float* __restrict__ stats, int N) {
    __shared__ float sW[HDIM * 128];         // 32 KB
    __shared__ float srow[32 * 65];          // +1 pad
    __shared__ float red[256];
    int tid = threadIdx.x;
    for (int i = tid; i < HDIM * 128 / 4; i += 256)
        ((float4*)sW)[i] = ((const float4*)W1)[i];
    int tx = tid & 31, ty = tid >> 5;
    float4 bv = *(const float4*)&b1[4 * tx];
    float s0 = 0, s1 = 0, s2 = 0, s3 = 0, q0 = 0, q1 = 0, q2 = 0, q3 = 0;
    int ntiles = (N + 31) >> 5;
    for (int tile = blockIdx.x; tile < ntiles; tile += gridDim.x) {
        int base = tile << 5;
        __syncthreads();
        for (int i = tid; i < 32 * HDIM; i += 256) {
            int r = i >> 6, cc = i & 63;
            int node = base + r;
            srow[r * 65 + cc] = (node < N) ? in[(size_t)node * HDIM + cc] : 0.f;
        }
        __syncthreads();
        float acc[4][4];
#pragma unroll
        for (int j = 0; j < 4; j++) { acc[j][0] = bv.x; acc[j][1] = bv.y; acc[j][2] = bv.z; acc[j][3] = bv.w; }
#pragma unroll 8
        for (int k = 0; k < HDIM; k++) {
            float4 wv = *(const float4*)&sW[k * 128 + 4 * tx];
            float r0 = srow[(ty * 4 + 0) * 65 + k];
            float r1 = srow[(ty * 4 + 1) * 65 + k];
            float r2 = srow[(ty * 4 + 2) * 65 + k];
            float r3 = srow[(ty * 4 + 3) * 65 + k];
            acc[0][0] += r0 * wv.x; acc[0][1] += r0 * wv.y; acc[0][2] += r0 * wv.z; acc[0][3] += r0 * wv.w;
            acc[1][0] += r1 * wv.x; acc[1][1] += r1 * wv.y; acc[1][2] += r1 * wv.z; acc[1][3] += r1 * wv.w;
            acc[2][0] += r2 * wv.x; acc[2][1] += r2 * wv.y; acc[2][2] += r2 * wv.z; acc[2][3] += r2 * wv.w;
            acc[3][0] += r3 * wv.x; acc[3][1] += r3 * wv.y; acc[3][2] += r3 * wv.z; acc[3][3] += r3 * wv.w;
        }
#pragma unroll
        for (int j = 0; j < 4; j++) {
            int node = base + ty * 4 + j;
            if (node < N) {
                *(float4*)&h1[(size_t)node * 128 + 4 * tx] =
                    make_float4(acc[j][0], acc[j][1], acc[j][2], acc[j][3]);
                s0 += acc[j][0]; q0 += acc[j][0] * acc[j][0];
                s1 += acc[j][1]; q1 += acc[j][1] * acc[j][1];
                s2 += acc[j][2]; q2 += acc[j][2] * acc[j][2];
                s3 += acc[j][3]; q3 += acc[j][3] * acc[j][3];
            }
        }
    }
    float sq[8] = { s0, s1, s2, s3, q0, q1, q2, q3 };
#pragma unroll
    for (int q = 0; q < 8; q++) {
        __syncthreads();
        red[tid] = sq[q];
        __syncthreads();
        if (tid < 32) {
            float t = 0.f;
#pragma unroll
            for (int k = 0; k < 8; k++) t += red[tid + 32 * k];
            atomicAdd(&stats[(q < 4 ? 0 : 128) + 4 * tid + (q & 3)], t);
        }
    }
}

// ---------------------------------------------------------------- MLP part 2
// h += relu(BN(h1)) @ W2 + b2; grid-stride tiles; round-3 inner loop;
// epilogue: stats of NEW h (for next layer's BN)
__global__ __launch_bounds__(256) void mlp2_kernel(
        const float* __restrict__ h1, const float* __restrict__ stats,
        const float* __restrict__ mg, const float* __restrict__ mb,
        const float* __restrict__ W2, const float* __restrict__ b2,
        float* __restrict__ h, float* __restrict__ nstats, int N) {
    __shared__ float sW[128 * HDIM];         // 32 KB
    __shared__ float sact[32 * 129];         // +1 pad
    __shared__ float sbn[512];               // mu | rs | gamma | beta
    __shared__ float red[256];
    int tid = threadIdx.x;
    for (int i = tid; i < 128 * HDIM / 4; i += 256)
        ((float4*)sW)[i] = ((const float4*)W2)[i];
    if (tid < 128) {
        float inv = 1.0f / (float)N;
        float mu  = stats[tid] * inv;
        float var = stats[128 + tid] * inv - mu * mu;
        sbn[tid]       = mu;
        sbn[128 + tid] = rsqrtf(var + 1e-5f);
        sbn[256 + tid] = mg[tid];
        sbn[384 + tid] = mb[tid];
    }
    int tx = tid & 15, ty = tid >> 4;
    float4 bv = *(const float4*)&b2[4 * tx];
    float s0 = 0, s1 = 0, s2 = 0, s3 = 0, q0 = 0, q1 = 0, q2 = 0, q3 = 0;
    int ntiles = (N + 31) >> 5;
    for (int tile = blockIdx.x; tile < ntiles; tile += gridDim.x) {
        int base = tile << 5;
        __syncthreads();
        for (int i = tid; i < 32 * 128; i += 256) {
            int r = i >> 7, o = i & 127;
            int node = base + r;
            float v = 0.f;
            if (node < N) {
                v = h1[(size_t)node * 128 + o];
                v = fmaxf((v - sbn[o]) * sbn[128 + o] * sbn[256 + o] + sbn[384 + o], 0.f);
            }
            sact[r * 129 + o] = v;
        }
        __syncthreads();
        float acc[2][4];
#pragma unroll
        for (int j = 0; j < 2; j++) { acc[j][0] = bv.x; acc[j][1] = bv.y; acc[j][2] = bv.z; acc[j][3] = bv.w; }
#pragma unroll 8
        for (int k = 0; k < 128; k++) {
            float4 wv = *(const float4*)&sW[k * HDIM + 4 * tx];
            float r0 = sact[(ty * 2 + 0) * 129 + k];
            float r1 = sact[(ty * 2 + 1) * 129 + k];
            acc[0][0] += r0 * wv.x; acc[0][1] += r0 * wv.y; acc[0][2] += r0 * wv.z; acc[0][3] += r0 * wv.w;
            acc[1][0] += r1 * wv.x; acc[1][1] += r1 * wv.y; acc[1][2] += r1 * wv.z; acc[1][3] += r1 * wv.w;
        }
#pragma unroll
        for (int j = 0; j < 2; j++) {
            int node = base + ty * 2 + j;
            if (node < N) {
                float4* p = (float4*)&h[(size_t)node * HDIM + 4 * tx];
                float4 old = *p;
                float4 nv = make_float4(old.x + acc[j][0], old.y + acc[j][1],
                                        old.z + acc[j][2], old.w + acc[j][3]);
                *p = nv;
                s0 += nv.x; q0 += nv.x * nv.x;
                s1 += nv.y; q1 += nv.y * nv.y;
                s2 += nv.z; q2 += nv.z * nv.z;
                s3 += nv.w; q3 += nv.w * nv.w;
            }
        }
    }
    float sq[8] = { s0, s1, s2, s3, q0, q1, q2, q3 };
#pragma unroll
    for (int q = 0; q < 8; q++) {
        __syncthreads();
        red[tid] = sq[q];
        __syncthreads();
        if (tid < 16) {
            float t = 0.f;
#pragma unroll
            for (int k = 0; k < 16; k++) t += red[tid + 16 * k];
            atomicAdd(&nstats[(q < 4 ? 0 : 64) + 4 * tid + (q & 3)], t);
        }
    }
}

// ---------------------------------------------------------------- pool + head
__global__ void pool_out_kernel(const float* __restrict__ h, const int* __restrict__ gstart,
                                const float* __restrict__ Wo, const float* __restrict__ bo,
                                float* __restrict__ out, int N) {
    __shared__ float sp[HDIM];
    __shared__ float red[256];
    __shared__ float sW[HDIM * COUT];
    int g = blockIdx.x;
    int tid = threadIdx.x;
    for (int i = tid; i < HDIM * COUT; i += 256) sW[i] = Wo[i];
    int beg = gstart[g], end = gstart[g + 1];
    int c = tid & 63, r0 = tid >> 6;
    float s = 0.f;
    for (int r = beg + r0; r < end; r += 4) s += h[(size_t)r * HDIM + c];
    red[tid] = s;
    __syncthreads();
    if (tid < HDIM) {
        s = red[tid] + red[tid + 64] + red[tid + 128] + red[tid + 192];
        float cnt = (float)(end - beg);
        float pooled = s / fmaxf(cnt, 1.0f);
        sp[tid] = fmaxf(pooled, 0.0f);
    }
    __syncthreads();
    if (tid < COUT) {
        float acc = bo[tid];
#pragma unroll
        for (int k = 0; k < HDIM; k++) acc += sp[k] * sW[k * COUT + tid];
        out[g * COUT + tid] = acc;
    }
}

// ================================================================ launch
extern "C" void kernel_launch(void* const* d_in, const int* in_sizes, int n_in,
                              void* d_out, int out_size, void* d_ws, size_t ws_size,
                              hipStream_t stream) {
    (void)in_sizes; (void)n_in; (void)out_size;
    const float* x          = (const float*)d_in[0];
    const int*   eidx       = (const int*)  d_in[1];
    const float* eattr      = (const float*)d_in[2];
    const int*   batch      = (const int*)  d_in[3];
    const float* lin_in_w   = (const float*)d_in[4];
    const float* lin_in_b   = (const float*)d_in[5];
    const float* norm_gamma = (const float*)d_in[6];
    const float* norm_beta  = (const float*)d_in[7];
    const float* edge_w     = (const float*)d_in[8];
    const float* edge_b     = (const float*)d_in[9];
    const float* tparam     = (const float*)d_in[10];
    const float* mlp_w1     = (const float*)d_in[11];
    const float* mlp_b1     = (const float*)d_in[12];
    const float* mlp_gamma  = (const float*)d_in[13];
    const float* mlp_beta   = (const float*)d_in[14];
    const float* mlp_w2     = (const float*)d_in[15];
    const float* mlp_b2     = (const float*)d_in[16];
    const float* lin_out_w  = (const float*)d_in[17];
    const float* lin_out_b  = (const float*)d_in[18];
    float* out = (float*)d_out;

    const int* src = eidx;
    const int* dst = eidx + N_EDGES;

    char* ws = (char*)d_ws;
    size_t off = 0;
    auto alloc = [&](size_t bytes) -> char* {
        char* p = ws + off;
        off = (off + bytes + 255) & ~(size_t)255;
        return p;
    };
    // zero-init region first: histogram + all BN stat accumulators
    int*   cnt     = (int*)  alloc((size_t)N_NODES * 4);
    float* statsA0 = (float*)alloc(128 * 4);   // h stats, layer 0
    float* statsB0 = (float*)alloc(256 * 4);   // h1 stats, layer 0
    float* statsA1 = (float*)alloc(128 * 4);   // h stats, layer 1 (from mlp2 l0)
    float* statsB1 = (float*)alloc(256 * 4);   // h1 stats, layer 1
    float* statsA2 = (float*)alloc(128 * 4);   // dummy sink (mlp2 l1)
    size_t zero_bytes = off;
    int*   bsum    = (int*)  alloc(256 * 4);
    int*   offsets = (int*)  alloc((size_t)(N_NODES + 1) * 4);
    int*   cursor  = (int*)  alloc((size_t)N_NODES * 4);
    int*   sorted  = (int*)  alloc((size_t)N_EDGES * 4);
    int*   gstart  = (int*)  alloc((size_t)(NGRAPH + 1) * 4);
    float* h       = (float*)alloc((size_t)N_NODES * HDIM * 4);
    float* ob      = (float*)alloc((size_t)N_NODES * HDIM * 4);
    float* h1      = (float*)alloc((size_t)N_NODES * 2 * HDIM * 4);
    // optional fast-path buffers (54.4 MB): edge data permuted into dst order
    size_t need_fast = off + (size_t)N_EDGES * 4 + 256 + (size_t)N_EDGES * EDIM * 4 + 256;
    bool fast = (ws_size >= need_fast);
    int*   src_sorted = nullptr;
    float* ea_sorted  = nullptr;
    if (fast) {
        src_sorted = (int*)  alloc((size_t)N_EDGES * 4);
        ea_sorted  = (float*)alloc((size_t)N_EDGES * EDIM * 4);
    }

    hipMemsetAsync(d_ws, 0, zero_bytes, stream);

    const int NB = (N_NODES + 255) / 256;
    hist_kernel      <<<(N_EDGES + 255) / 256, 256, 0, stream>>>(dst, cnt, N_EDGES);
    scan_part_kernel <<<NB, 256, 0, stream>>>(cnt, bsum, N_NODES);
    scan_top_kernel  <<<1, 256, 0, stream>>>(bsum, NB);
    scan_apply_kernel<<<NB, 256, 0, stream>>>(cnt, bsum, offsets, cursor, N_NODES);
    scatter_kernel   <<<(N_EDGES + 255) / 256, 256, 0, stream>>>(dst, cursor, sorted, N_EDGES);
    if (fast)
        permute_kernel<<<(N_EDGES * 4 + 255) / 256, 256, 0, stream>>>(
            sorted, src, (const float4*)eattr, (float4*)ea_sorted, src_sorted, N_EDGES);
    gstart_kernel    <<<NB, 256, 0, stream>>>(batch, gstart, N_NODES, NGRAPH);
    lin_in_kernel    <<<256, 256, 0, stream>>>(x, lin_in_w, lin_in_b, h, statsA0, N_NODES);

    float* statsA[3] = { statsA0, statsA1, statsA2 };
    float* statsB[2] = { statsB0, statsB1 };
    const int MLPG = 768;                    // grid-stride blocks for MLPs
    for (int l = 0; l < 2; l++) {
        agg_kernel<<<(N_NODES + 3) / 4, 256, 0, stream>>>(
            h,
            fast ? src_sorted : src,
            fast ? ea_sorted : eattr,
            edge_w + (size_t)l * EDIM * HDIM, edge_b + l * HDIM,
            tparam + l, statsA[l], norm_gamma + l * HDIM, norm_beta + l * HDIM,
            offsets, fast ? nullptr : sorted, ob, N_NODES);
        mlp1_kernel<<<MLPG, 256, 0, stream>>>(
            ob, mlp_w1 + (size_t)l * HDIM * 2 * HDIM, mlp_b1 + l * 2 * HDIM,
            h1, statsB[l], N_NODES);
        mlp2_kernel<<<MLPG, 256, 0, stream>>>(
            h1, statsB[l], mlp_gamma + l * 2 * HDIM, mlp_beta + l * 2 * HDIM,
            mlp_w2 + (size_t)l * 2 * HDIM * HDIM, mlp_b2 + l * HDIM,
            h, statsA[l + 1], N_NODES);
    }
    pool_out_kernel<<<NGRAPH, 256, 0, stream>>>(h, gstart, lin_out_w, lin_out_b, out, N_NODES);
}

// Round 6
// 862.712 us; speedup vs baseline: 1.4566x; 1.0979x over previous
//
#include <hip/hip_runtime.h>

#define N_NODES 50000
#define N_EDGES 800000
#define F_INP   32
#define HDIM    64
#define EDIM    16
#define COUT    40
#define NGRAPH  64

// ---------------------------------------------------------------- sort by dst
__global__ void hist_kernel(const int* __restrict__ dst, int* __restrict__ cnt, int E) {
    int e = blockIdx.x * 256 + threadIdx.x;
    if (e < E) atomicAdd(&cnt[dst[e]], 1);
}

__global__ void scan_part_kernel(const int* __restrict__ cnt, int* __restrict__ bsum, int n) {
    __shared__ int red[256];
    int tid = threadIdx.x;
    int idx = blockIdx.x * 256 + tid;
    red[tid] = (idx < n) ? cnt[idx] : 0;
    __syncthreads();
    for (int off = 128; off > 0; off >>= 1) {
        if (tid < off) red[tid] += red[tid + off];
        __syncthreads();
    }
    if (tid == 0) bsum[blockIdx.x] = red[0];
}

__global__ void scan_top_kernel(int* __restrict__ bsum, int nb) {
    __shared__ int tmp[256];
    int tid = threadIdx.x;
    int v = (tid < nb) ? bsum[tid] : 0;
    tmp[tid] = v;
    __syncthreads();
    for (int off = 1; off < 256; off <<= 1) {
        int x = (tid >= off) ? tmp[tid - off] : 0;
        __syncthreads();
        tmp[tid] += x;
        __syncthreads();
    }
    if (tid < nb) bsum[tid] = tmp[tid] - v;   // exclusive
}

__global__ void scan_apply_kernel(const int* __restrict__ cnt, const int* __restrict__ bsum,
                                  int* __restrict__ offsets, int* __restrict__ cursor, int n) {
    __shared__ int tmp[256];
    int tid = threadIdx.x;
    int idx = blockIdx.x * 256 + tid;
    int v = (idx < n) ? cnt[idx] : 0;
    tmp[tid] = v;
    __syncthreads();
    for (int off = 1; off < 256; off <<= 1) {
        int x = (tid >= off) ? tmp[tid - off] : 0;
        __syncthreads();
        tmp[tid] += x;
        __syncthreads();
    }
    int excl = tmp[tid] - v + bsum[blockIdx.x];
    if (idx < n) { offsets[idx] = excl; cursor[idx] = excl; }
    if (idx == n - 1) offsets[n] = excl + v;
}

__global__ void scatter_kernel(const int* __restrict__ dst, int* __restrict__ cursor,
                               int* __restrict__ sorted, int E) {
    int e = blockIdx.x * 256 + threadIdx.x;
    if (e < E) {
        int p = atomicAdd(&cursor[dst[e]], 1);
        sorted[p] = e;
    }
}

// gather edge_attr + src into dst-sorted order (streaming reads thereafter)
__global__ void permute_kernel(const int* __restrict__ sorted, const int* __restrict__ src,
                               const float4* __restrict__ ea, float4* __restrict__ ea_s,
                               int* __restrict__ src_s, int E) {
    int t = blockIdx.x * 256 + threadIdx.x;
    int j = t >> 2, q = t & 3;
    if (j >= E) return;
    int e = sorted[j];
    ea_s[(size_t)j * 4 + q] = ea[(size_t)e * 4 + q];
    if (q == 0) src_s[j] = src[e];
}

// batch is sorted ascending; find graph start offsets
__global__ void gstart_kernel(const int* __restrict__ batch, int* __restrict__ gstart,
                              int N, int G) {
    int n = blockIdx.x * 256 + threadIdx.x;
    if (n >= N) return;
    int g  = batch[n];
    int gp = (n == 0) ? -1 : batch[n - 1];
    for (int gg = gp + 1; gg <= g; gg++) gstart[gg] = n;
    if (n == N - 1) {
        for (int gg = g + 1; gg <= G; gg++) gstart[gg] = N;
    }
}

// ---------------------------------------------------------------- input linear
// h = x @ W + b  (N,32)@(32,64); grid-stride; epilogue: h stats (sum, sumsq)
__global__ void lin_in_kernel(const float* __restrict__ x, const float* __restrict__ W,
                              const float* __restrict__ b, float* __restrict__ h,
                              float* __restrict__ nstats, int N) {
    __shared__ float red[256];
    int tid = threadIdx.x;
    int c = tid & 63;
    float w[F_INP];
#pragma unroll
    for (int k = 0; k < F_INP; k++) w[k] = W[k * HDIM + c];
    float bc = b[c];
    float s = 0.f, ss = 0.f;
    for (int node = blockIdx.x * 4 + (tid >> 6); node < N; node += gridDim.x * 4) {
        const float4* xr = (const float4*)(x + (size_t)node * F_INP);
        float acc = bc;
#pragma unroll
        for (int k4 = 0; k4 < F_INP / 4; k4++) {
            float4 xv = xr[k4];
            acc += xv.x * w[4 * k4] + xv.y * w[4 * k4 + 1]
                 + xv.z * w[4 * k4 + 2] + xv.w * w[4 * k4 + 3];
        }
        h[(size_t)node * HDIM + c] = acc;
        s += acc; ss += acc * acc;
    }
    __syncthreads();
    red[tid] = s;
    __syncthreads();
    if (tid < 64) atomicAdd(&nstats[tid], red[tid] + red[tid + 64] + red[tid + 128] + red[tid + 192]);
    __syncthreads();
    red[tid] = ss;
    __syncthreads();
    if (tid < 64) atomicAdd(&nstats[64 + tid], red[tid] + red[tid + 64] + red[tid + 128] + red[tid + 192]);
}

// ---------------------------------------------------------------- aggregation
// one wave per node (lane = channel). BN+ReLU of h fused (z = hv*A + B form).
// Fast path: ea/srcarr pre-permuted to dst-sorted order; 1-deep prefetch of
// the random h[s] gather overlaps latency with the 16-FMA edge embedding.
// No seg_max: m in [1e-7,~8], exp cannot overflow; softmax shift-invariant.
__global__ void agg_kernel(const float* __restrict__ h, const int* __restrict__ srcarr,
                           const float* __restrict__ ea, const float* __restrict__ We,
                           const float* __restrict__ be, const float* __restrict__ tptr,
                           const float* __restrict__ stats,
                           const float* __restrict__ gamma, const float* __restrict__ beta,
                           const int* __restrict__ offsets, const int* __restrict__ sorted,
                           float* __restrict__ out, int N) {
    int tid = threadIdx.x;
    int c = tid & 63;
    float inv = 1.0f / (float)N;
    float mu  = stats[c] * inv;
    float var = stats[HDIM + c] * inv - mu * mu;
    float rs  = rsqrtf(var + 1e-5f);
    float A   = rs * gamma[c];
    float B   = beta[c] - mu * A;
    float w[EDIM];
#pragma unroll
    for (int k = 0; k < EDIM; k++) w[k] = We[k * HDIM + c];
    float bc = be[c];
    float tval = *tptr;
    int node = blockIdx.x * 4 + (tid >> 6);
    if (node >= N) return;
    int beg = offsets[node], end = offsets[node + 1];
    float denom = 0.f, num = 0.f;
    if (sorted == nullptr) {
        // fast path: edges [beg,end) are contiguous in ea/srcarr
        for (int cb = beg; cb < end; cb += 64) {
            int nc = end - cb; if (nc > 64) nc = 64;
            int s_l = 0;
            if (c < nc) s_l = srcarr[cb + c];
            int s0 = __shfl(s_l, 0);
            float hv_n = h[(size_t)s0 * HDIM + c];
            const float4* ar = (const float4*)(ea + (size_t)cb * EDIM);
            for (int j = 0; j < nc; j++) {
                float hv = hv_n;
                int jn = (j + 1 < nc) ? j + 1 : j;
                int sn = __shfl(s_l, jn);
                hv_n = h[(size_t)sn * HDIM + c];     // prefetch next gather
                float4 a0 = ar[0], a1 = ar[1], a2 = ar[2], a3 = ar[3];
                ar += 4;
                float acc = bc
                    + a0.x * w[0]  + a0.y * w[1]  + a0.z * w[2]  + a0.w * w[3]
                    + a1.x * w[4]  + a1.y * w[5]  + a1.z * w[6]  + a1.w * w[7]
                    + a2.x * w[8]  + a2.y * w[9]  + a2.z * w[10] + a2.w * w[11]
                    + a3.x * w[12] + a3.y * w[13] + a3.z * w[14] + a3.w * w[15];
                float zv = fmaxf(hv * A + B, 0.f);
                float m  = fmaxf(zv + acc, 0.f) + 1e-7f;
                float ex = __expf(m * tval);
                denom += ex;
                num   += ex * m;
            }
        }
    } else {
        for (int cb = beg; cb < end; cb += 64) {
            int nc = end - cb; if (nc > 64) nc = 64;
            int e_l = 0, s_l = 0;
            if (c < nc) { e_l = sorted[cb + c]; s_l = srcarr[e_l]; }
            for (int j = 0; j < nc; j++) {
                int e = __shfl(e_l, j);
                int s = __shfl(s_l, j);
                const float4* ar = (const float4*)(ea + (size_t)e * EDIM);
                float4 a0 = ar[0], a1 = ar[1], a2 = ar[2], a3 = ar[3];
                float acc = bc
                    + a0.x * w[0]  + a0.y * w[1]  + a0.z * w[2]  + a0.w * w[3]
                    + a1.x * w[4]  + a1.y * w[5]  + a1.z * w[6]  + a1.w * w[7]
                    + a2.x * w[8]  + a2.y * w[9]  + a2.z * w[10] + a2.w * w[11]
                    + a3.x * w[12] + a3.y * w[13] + a3.z * w[14] + a3.w * w[15];
                float hv = h[(size_t)s * HDIM + c];
                float zv = fmaxf(hv * A + B, 0.f);
                float m  = fmaxf(zv + acc, 0.f) + 1e-7f;
                float ex = __expf(m * tval);
                denom += ex;
                num   += ex * m;
            }
        }
    }
    float hv = h[(size_t)node * HDIM + c];
    float zn = fmaxf(hv * A + B, 0.f);
    out[(size_t)node * HDIM + c] = num / (denom + 1e-16f) + zn;
}

// ---------------------------------------------------------------- MLP part 1
// h1 = in @ W1 + b1  (N,64)@(64,128); float4 LDS reads everywhere (activation
// reads are 32-thread broadcasts -> conflict-free); bounded unroll + VGPR cap
// via launch_bounds(256,3) so the R4 spill cliff cannot recur.
__global__ __launch_bounds__(256, 3) void mlp1_kernel(
        const float* __restrict__ in, const float* __restrict__ W1,
        const float* __restrict__ b1, float* __restrict__ h1,
        float* __restrict__ stats, int N) {
    __shared__ float sW[HDIM * 128];         // 32 KB
    __shared__ float srow[32 * 68];          // 8.5 KB, 16B-aligned rows
    __shared__ float red[256];
    int tid = threadIdx.x;
    for (int i = tid; i < HDIM * 128 / 4; i += 256)
        ((float4*)sW)[i] = ((const float4*)W1)[i];
    int tx = tid & 31, ty = tid >> 5;
    float4 bv = *(const float4*)&b1[4 * tx];
    float s0 = 0, s1 = 0, s2 = 0, s3 = 0, q0 = 0, q1 = 0, q2 = 0, q3 = 0;
    int ntiles = (N + 31) >> 5;
    for (int tile = blockIdx.x; tile < ntiles; tile += gridDim.x) {
        int base = tile << 5;
        __syncthreads();
        for (int i = tid; i < 32 * 16; i += 256) {
            int r = i >> 4, q = i & 15;
            int node = base + r;
            float4 v = make_float4(0.f, 0.f, 0.f, 0.f);
            if (node < N) v = *(const float4*)&in[(size_t)node * HDIM + 4 * q];
            *(float4*)&srow[r * 68 + 4 * q] = v;
        }
        __syncthreads();
        float acc[4][4];
#pragma unroll
        for (int j = 0; j < 4; j++) { acc[j][0] = bv.x; acc[j][1] = bv.y; acc[j][2] = bv.z; acc[j][3] = bv.w; }
#pragma unroll 4
        for (int k4 = 0; k4 < 16; k4++) {
            float4 rv0 = *(const float4*)&srow[(ty * 4 + 0) * 68 + 4 * k4];
            float4 rv1 = *(const float4*)&srow[(ty * 4 + 1) * 68 + 4 * k4];
            float4 rv2 = *(const float4*)&srow[(ty * 4 + 2) * 68 + 4 * k4];
            float4 rv3 = *(const float4*)&srow[(ty * 4 + 3) * 68 + 4 * k4];
#pragma unroll
            for (int kk = 0; kk < 4; kk++) {
                float4 wv = *(const float4*)&sW[(4 * k4 + kk) * 128 + 4 * tx];
                float f0 = ((const float*)&rv0)[kk];
                float f1 = ((const float*)&rv1)[kk];
                float f2 = ((const float*)&rv2)[kk];
                float f3 = ((const float*)&rv3)[kk];
                acc[0][0] += f0 * wv.x; acc[0][1] += f0 * wv.y; acc[0][2] += f0 * wv.z; acc[0][3] += f0 * wv.w;
                acc[1][0] += f1 * wv.x; acc[1][1] += f1 * wv.y; acc[1][2] += f1 * wv.z; acc[1][3] += f1 * wv.w;
                acc[2][0] += f2 * wv.x; acc[2][1] += f2 * wv.y; acc[2][2] += f2 * wv.z; acc[2][3] += f2 * wv.w;
                acc[3][0] += f3 * wv.x; acc[3][1] += f3 * wv.y; acc[3][2] += f3 * wv.z; acc[3][3] += f3 * wv.w;
            }
        }
#pragma unroll
        for (int j = 0; j < 4; j++) {
            int node = base + ty * 4 + j;
            if (node < N) {
                *(float4*)&h1[(size_t)node * 128 + 4 * tx] =
                    make_float4(acc[j][0], acc[j][1], acc[j][2], acc[j][3]);
                s0 += acc[j][0]; q0 += acc[j][0] * acc[j][0];
                s1 += acc[j][1]; q1 += acc[j][1] * acc[j][1];
                s2 += acc[j][2]; q2 += acc[j][2] * acc[j][2];
                s3 += acc[j][3]; q3 += acc[j][3] * acc[j][3];
            }
        }
    }
    float sq[8] = { s0, s1, s2, s3, q0, q1, q2, q3 };
#pragma unroll
    for (int q = 0; q < 8; q++) {
        __syncthreads();
        red[tid] = sq[q];
        __syncthreads();
        if (tid < 32) {
            float t = 0.f;
#pragma unroll
            for (int k = 0; k < 8; k++) t += red[tid + 32 * k];
            atomicAdd(&stats[(q < 4 ? 0 : 128) + 4 * tid + (q & 3)], t);
        }
    }
}

// ---------------------------------------------------------------- MLP part 2
// h += relu(BN(h1)) @ W2 + b2; float4 LDS reads; epilogue: stats of NEW h
__global__ __launch_bounds__(256, 3) void mlp2_kernel(
        const float* __restrict__ h1, const float* __restrict__ stats,
        const float* __restrict__ mg, const float* __restrict__ mb,
        const float* __restrict__ W2, const float* __restrict__ b2,
        float* __restrict__ h, float* __restrict__ nstats, int N) {
    __shared__ float sW[128 * HDIM];         // 32 KB
    __shared__ float sact[32 * 132];         // 16.5 KB, 16B-aligned rows
    __shared__ float sbn[512];               // mu | rs | gamma | beta
    __shared__ float red[256];
    int tid = threadIdx.x;
    for (int i = tid; i < 128 * HDIM / 4; i += 256)
        ((float4*)sW)[i] = ((const float4*)W2)[i];
    if (tid < 128) {
        float inv = 1.0f / (float)N;
        float mu  = stats[tid] * inv;
        float var = stats[128 + tid] * inv - mu * mu;
        sbn[tid]       = mu;
        sbn[128 + tid] = rsqrtf(var + 1e-5f);
        sbn[256 + tid] = mg[tid];
        sbn[384 + tid] = mb[tid];
    }
    int tx = tid & 15, ty = tid >> 4;
    float4 bv = *(const float4*)&b2[4 * tx];
    float s0 = 0, s1 = 0, s2 = 0, s3 = 0, q0 = 0, q1 = 0, q2 = 0, q3 = 0;
    int ntiles = (N + 31) >> 5;
    for (int tile = blockIdx.x; tile < ntiles; tile += gridDim.x) {
        int base = tile << 5;
        __syncthreads();
        for (int i = tid; i < 32 * 32; i += 256) {
            int r = i >> 5, q = i & 31;
            int node = base + r;
            float4 v = make_float4(0.f, 0.f, 0.f, 0.f);
            if (node < N) {
                v = *(const float4*)&h1[(size_t)node * 128 + 4 * q];
                int o = 4 * q;
                v.x = fmaxf((v.x - sbn[o + 0]) * sbn[128 + o + 0] * sbn[256 + o + 0] + sbn[384 + o + 0], 0.f);
                v.y = fmaxf((v.y - sbn[o + 1]) * sbn[128 + o + 1] * sbn[256 + o + 1] + sbn[384 + o + 1], 0.f);
                v.z = fmaxf((v.z - sbn[o + 2]) * sbn[128 + o + 2] * sbn[256 + o + 2] + sbn[384 + o + 2], 0.f);
                v.w = fmaxf((v.w - sbn[o + 3]) * sbn[128 + o + 3] * sbn[256 + o + 3] + sbn[384 + o + 3], 0.f);
            }
            *(float4*)&sact[r * 132 + 4 * q] = v;
        }
        __syncthreads();
        float acc[2][4];
#pragma unroll
        for (int j = 0; j < 2; j++) { acc[j][0] = bv.x; acc[j][1] = bv.y; acc[j][2] = bv.z; acc[j][3] = bv.w; }
#pragma unroll 4
        for (int k4 = 0; k4 < 32; k4++) {
            float4 rv0 = *(const float4*)&sact[(ty * 2 + 0) * 132 + 4 * k4];
            float4 rv1 = *(const float4*)&sact[(ty * 2 + 1) * 132 + 4 * k4];
#pragma unroll
            for (int kk = 0; kk < 4; kk++) {
                float4 wv = *(const float4*)&sW[(4 * k4 + kk) * HDIM + 4 * tx];
                float f0 = ((const float*)&rv0)[kk];
                float f1 = ((const float*)&rv1)[kk];
                acc[0][0] += f0 * wv.x; acc[0][1] += f0 * wv.y; acc[0][2] += f0 * wv.z; acc[0][3] += f0 * wv.w;
                acc[1][0] += f1 * wv.x; acc[1][1] += f1 * wv.y; acc[1][2] += f1 * wv.z; acc[1][3] += f1 * wv.w;
            }
        }
#pragma unroll
        for (int j = 0; j < 2; j++) {
            int node = base + ty * 2 + j;
            if (node < N) {
                float4* p = (float4*)&h[(size_t)node * HDIM + 4 * tx];
                float4 old = *p;
                float4 nv = make_float4(old.x + acc[j][0], old.y + acc[j][1],
                                        old.z + acc[j][2], old.w + acc[j][3]);
                *p = nv;
                s0 += nv.x; q0 += nv.x * nv.x;
                s1 += nv.y; q1 += nv.y * nv.y;
                s2 += nv.z; q2 += nv.z * nv.z;
                s3 += nv.w; q3 += nv.w * nv.w;
            }
        }
    }
    float sq[8] = { s0, s1, s2, s3, q0, q1, q2, q3 };
#pragma unroll
    for (int q = 0; q < 8; q++) {
        __syncthreads();
        red[tid] = sq[q];
        __syncthreads();
        if (tid < 16) {
            float t = 0.f;
#pragma unroll
            for (int k = 0; k < 16; k++) t += red[tid + 16 * k];
            atomicAdd(&nstats[(q < 4 ? 0 : 64) + 4 * tid + (q & 3)], t);
        }
    }
}

// ---------------------------------------------------------------- pool + head
// 1024 threads/block: 16 rows in flight -> dependent-load chain 4x shorter
__global__ __launch_bounds__(1024) void pool_out_kernel(
        const float* __restrict__ h, const int* __restrict__ gstart,
        const float* __restrict__ Wo, const float* __restrict__ bo,
        float* __restrict__ out, int N) {
    __shared__ float sp[HDIM];
    __shared__ float red[1024];
    __shared__ float sW[HDIM * COUT];
    int g = blockIdx.x;
    int tid = threadIdx.x;
    for (int i = tid; i < HDIM * COUT; i += 1024) sW[i] = Wo[i];
    int beg = gstart[g], end = gstart[g + 1];
    int c = tid & 63, r0 = tid >> 6;            // 16 row-streams
    float s = 0.f;
    for (int r = beg + r0; r < end; r += 16) s += h[(size_t)r * HDIM + c];
    red[tid] = s;
    __syncthreads();
    if (tid < HDIM) {
        s = 0.f;
#pragma unroll
        for (int k = 0; k < 16; k++) s += red[tid + 64 * k];
        float cnt = (float)(end - beg);
        float pooled = s / fmaxf(cnt, 1.0f);
        sp[tid] = fmaxf(pooled, 0.0f);
    }
    __syncthreads();
    if (tid < COUT) {
        float acc = bo[tid];
#pragma unroll
        for (int k = 0; k < HDIM; k++) acc += sp[k] * sW[k * COUT + tid];
        out[g * COUT + tid] = acc;
    }
}

// ================================================================ launch
extern "C" void kernel_launch(void* const* d_in, const int* in_sizes, int n_in,
                              void* d_out, int out_size, void* d_ws, size_t ws_size,
                              hipStream_t stream) {
    (void)in_sizes; (void)n_in; (void)out_size;
    const float* x          = (const float*)d_in[0];
    const int*   eidx       = (const int*)  d_in[1];
    const float* eattr      = (const float*)d_in[2];
    const int*   batch      = (const int*)  d_in[3];
    const float* lin_in_w   = (const float*)d_in[4];
    const float* lin_in_b   = (const float*)d_in[5];
    const float* norm_gamma = (const float*)d_in[6];
    const float* norm_beta  = (const float*)d_in[7];
    const float* edge_w     = (const float*)d_in[8];
    const float* edge_b     = (const float*)d_in[9];
    const float* tparam     = (const float*)d_in[10];
    const float* mlp_w1     = (const float*)d_in[11];
    const float* mlp_b1     = (const float*)d_in[12];
    const float* mlp_gamma  = (const float*)d_in[13];
    const float* mlp_beta   = (const float*)d_in[14];
    const float* mlp_w2     = (const float*)d_in[15];
    const float* mlp_b2     = (const float*)d_in[16];
    const float* lin_out_w  = (const float*)d_in[17];
    const float* lin_out_b  = (const float*)d_in[18];
    float* out = (float*)d_out;

    const int* src = eidx;
    const int* dst = eidx + N_EDGES;

    char* ws = (char*)d_ws;
    size_t off = 0;
    auto alloc = [&](size_t bytes) -> char* {
        char* p = ws + off;
        off = (off + bytes + 255) & ~(size_t)255;
        return p;
    };
    // zero-init region first: histogram + all BN stat accumulators
    int*   cnt     = (int*)  alloc((size_t)N_NODES * 4);
    float* statsA0 = (float*)alloc(128 * 4);   // h stats, layer 0
    float* statsB0 = (float*)alloc(256 * 4);   // h1 stats, layer 0
    float* statsA1 = (float*)alloc(128 * 4);   // h stats, layer 1 (from mlp2 l0)
    float* statsB1 = (float*)alloc(256 * 4);   // h1 stats, layer 1
    float* statsA2 = (float*)alloc(128 * 4);   // dummy sink (mlp2 l1)
    size_t zero_bytes = off;
    int*   bsum    = (int*)  alloc(256 * 4);
    int*   offsets = (int*)  alloc((size_t)(N_NODES + 1) * 4);
    int*   cursor  = (int*)  alloc((size_t)N_NODES * 4);
    int*   sorted  = (int*)  alloc((size_t)N_EDGES * 4);
    int*   gstart  = (int*)  alloc((size_t)(NGRAPH + 1) * 4);
    float* h       = (float*)alloc((size_t)N_NODES * HDIM * 4);
    float* ob      = (float*)alloc((size_t)N_NODES * HDIM * 4);
    float* h1      = (float*)alloc((size_t)N_NODES * 2 * HDIM * 4);
    // optional fast-path buffers (54.4 MB): edge data permuted into dst order
    size_t need_fast = off + (size_t)N_EDGES * 4 + 256 + (size_t)N_EDGES * EDIM * 4 + 256;
    bool fast = (ws_size >= need_fast);
    int*   src_sorted = nullptr;
    float* ea_sorted  = nullptr;
    if (fast) {
        src_sorted = (int*)  alloc((size_t)N_EDGES * 4);
        ea_sorted  = (float*)alloc((size_t)N_EDGES * EDIM * 4);
    }

    hipMemsetAsync(d_ws, 0, zero_bytes, stream);

    const int NB = (N_NODES + 255) / 256;
    hist_kernel      <<<(N_EDGES + 255) / 256, 256, 0, stream>>>(dst, cnt, N_EDGES);
    scan_part_kernel <<<NB, 256, 0, stream>>>(cnt, bsum, N_NODES);
    scan_top_kernel  <<<1, 256, 0, stream>>>(bsum, NB);
    scan_apply_kernel<<<NB, 256, 0, stream>>>(cnt, bsum, offsets, cursor, N_NODES);
    scatter_kernel   <<<(N_EDGES + 255) / 256, 256, 0, stream>>>(dst, cursor, sorted, N_EDGES);
    if (fast)
        permute_kernel<<<(N_EDGES * 4 + 255) / 256, 256, 0, stream>>>(
            sorted, src, (const float4*)eattr, (float4*)ea_sorted, src_sorted, N_EDGES);
    gstart_kernel    <<<NB, 256, 0, stream>>>(batch, gstart, N_NODES, NGRAPH);
    lin_in_kernel    <<<256, 256, 0, stream>>>(x, lin_in_w, lin_in_b, h, statsA0, N_NODES);

    float* statsA[3] = { statsA0, statsA1, statsA2 };
    float* statsB[2] = { statsB0, statsB1 };
    const int MLPG = 768;                    // grid-stride blocks for MLPs
    for (int l = 0; l < 2; l++) {
        agg_kernel<<<(N_NODES + 3) / 4, 256, 0, stream>>>(
            h,
            fast ? src_sorted : src,
            fast ? ea_sorted : eattr,
            edge_w + (size_t)l * EDIM * HDIM, edge_b + l * HDIM,
            tparam + l, statsA[l], norm_gamma + l * HDIM, norm_beta + l * HDIM,
            offsets, fast ? nullptr : sorted, ob, N_NODES);
        mlp1_kernel<<<MLPG, 256, 0, stream>>>(
            ob, mlp_w1 + (size_t)l * HDIM * 2 * HDIM, mlp_b1 + l * 2 * HDIM,
            h1, statsB[l], N_NODES);
        mlp2_kernel<<<MLPG, 256, 0, stream>>>(
            h1, statsB[l], mlp_gamma + l * 2 * HDIM, mlp_beta + l * 2 * HDIM,
            mlp_w2 + (size_t)l * 2 * HDIM * HDIM, mlp_b2 + l * HDIM,
            h, statsA[l + 1], N_NODES);
    }
    pool_out_kernel<<<NGRAPH, 1024, 0, stream>>>(h, gstart, lin_out_w, lin_out_b, out, N_NODES);
}